// Round 1
// baseline (4224.529 us; speedup 1.0000x reference)
//
#include <hip/hip_runtime.h>

#define NB 32      // batch
#define NT 512     // time steps
#define NI 128     // input dim
#define NH 1024    // hidden dim
#define NG 4096    // 4*NH gate columns
#define NO 128     // output dim

typedef _Float16 f16;
typedef _Float16 f16x8 __attribute__((ext_vector_type(8)));
typedef float f32x4 __attribute__((ext_vector_type(4)));

__device__ __forceinline__ float sigm(float x) { return 1.f / (1.f + __expf(-x)); }
__device__ __forceinline__ float tanh_(float x) {
    // overflow-safe tanh via e^{-2|x|} in (0,1]
    float a = fabsf(x);
    float e = __expf(-2.f * a);
    float r = (1.f - e) / (1.f + e);
    return x < 0.f ? -r : r;
}

__global__ void convf16(const float* __restrict__ src, f16* __restrict__ dst, int n) {
    int i = blockIdx.x * blockDim.x + threadIdx.x;
    if (i < n) dst[i] = (f16)src[i];
}

// Stage a [32][1024] fp16 matrix (64 KB) into LDS with XOR swizzle
// (row stride 2048B is same-bank for ds_read_b128 without it).
__device__ __forceinline__ void stage_h(const f16* __restrict__ hsrc, char* smem, int tid) {
    const float4* src = (const float4*)hsrc;
#pragma unroll
    for (int i = 0; i < 16; ++i) {
        int c = i * 256 + tid;          // 16B chunk index, 4096 total
        int off = c * 16;
        int swz = off ^ (((off >> 11) & 7) << 4);
        *(float4*)(smem + swz) = src[c];
    }
}
__device__ __forceinline__ f16x8 afrag(const char* smem, int row, int kk) {
    int off = (row << 11) + kk * 2;
    off ^= ((row & 7) << 4);
    return *(const f16x8*)(smem + off);
}

// One pipeline interval k:
//   blk 0..63   stage B: h1[t=k-1] = lstm_step(xp1[t], h1[t-1], c1)   W_hh0
//   blk 64..127 stage C: xp2[t=k-2] = h1[t] @ W_ih1^T + b1            W_ih1
//   blk 128..191 stage D: h2[t=k-3] = lstm_step(xp2[t], h2[t-1], c2)  W_hh1
//   blk 192..207 stage A: xp1[t=k] = state[:,t,:] @ W_ih0^T + b0      W_ih0
// All consumed data was produced in earlier kernel launches (stream-ordered).
__global__ __launch_bounds__(256) void lstm_step(
    int k,
    const f16* __restrict__ state16,
    const f16* __restrict__ Wih0,
    const f16* __restrict__ Whh0,
    const f16* __restrict__ Wih1,
    const f16* __restrict__ Whh1,
    const float* __restrict__ b0,
    const float* __restrict__ b1,
    float* __restrict__ xp1,   // [2][NB][NG]
    float* __restrict__ xp2,   // [2][NB][NG]
    f16* __restrict__ h1r,     // [2][NB][NH]
    f16* __restrict__ h2r,     // [2][NB][NH]
    float* __restrict__ c1,    // [NB][NH]
    float* __restrict__ c2,    // [NB][NH]
    f16* __restrict__ h2all)   // [NT][NB][NH]
{
    __shared__ __align__(16) char smem[65536];
    const int blk = blockIdx.x;
    const int tid = threadIdx.x;
    const int wave = tid >> 6;
    const int lane = tid & 63;
    const int lhi = lane >> 4;
    const int llo = lane & 15;

    if (blk < 192) {
        const int stage = blk >> 6;     // 0=B, 1=C, 2=D
        const int wg = blk & 63;
        int t;
        if (stage == 0) t = k - 1;
        else if (stage == 1) t = k - 2;
        else t = k - 3;
        if (t < 0 || t >= NT) return;

        const f16* hsrc;
        const f16* W;
        if (stage == 0)      { hsrc = h1r + ((t + 1) & 1) * NB * NH; W = Whh0; }
        else if (stage == 1) { hsrc = h1r + (t & 1) * NB * NH;       W = Wih1; }
        else                 { hsrc = h2r + ((t + 1) & 1) * NB * NH; W = Whh1; }

        stage_h(hsrc, smem, tid);
        __syncthreads();

        const int U = wg * 16;                 // 16 hidden units per WG
        const int col = wave * NH + U + llo;   // wave = gate index (i,f,g,o)

        f32x4 acc0, acc1;
        if (stage == 1) {
            float bb = b1[col];
#pragma unroll
            for (int r = 0; r < 4; ++r) { acc0[r] = bb; acc1[r] = bb; }
        } else {
            const float* xin = (stage == 0 ? xp1 : xp2) + (size_t)(t & 1) * NB * NG;
#pragma unroll
            for (int r = 0; r < 4; ++r) {
                acc0[r] = xin[(lhi * 4 + r) * NG + col];
                acc1[r] = xin[(16 + lhi * 4 + r) * NG + col];
            }
        }

        const f16* wrow = W + (size_t)col * NH;
#pragma unroll 8
        for (int kt = 0; kt < 32; ++kt) {
            int kk = kt * 32 + lhi * 8;
            f16x8 a0 = afrag(smem, llo, kk);
            f16x8 a1 = afrag(smem, 16 + llo, kk);
            f16x8 bf = *(const f16x8*)(wrow + kk);
            acc0 = __builtin_amdgcn_mfma_f32_16x16x32_f16(a0, bf, acc0, 0, 0, 0);
            acc1 = __builtin_amdgcn_mfma_f32_16x16x32_f16(a1, bf, acc1, 0, 0, 0);
        }

        if (stage == 1) {
            float* xo = xp2 + (size_t)(t & 1) * NB * NG;
#pragma unroll
            for (int r = 0; r < 4; ++r) {
                xo[(lhi * 4 + r) * NG + col] = acc0[r];
                xo[(16 + lhi * 4 + r) * NG + col] = acc1[r];
            }
            return;
        }

        // exchange gates through LDS (reuse the h-staging region)
        __syncthreads();
        float* gb = (float*)smem;   // [4 gates][32 batch][16 units]
#pragma unroll
        for (int r = 0; r < 4; ++r) {
            gb[wave * 512 + (lhi * 4 + r) * 16 + llo] = acc0[r];
            gb[wave * 512 + (16 + lhi * 4 + r) * 16 + llo] = acc1[r];
        }
        __syncthreads();

        float* cst = (stage == 0) ? c1 : c2;
        f16* hout = ((stage == 0) ? h1r : h2r) + (size_t)(t & 1) * NB * NH;
#pragma unroll
        for (int i = tid; i < 512; i += 256) {
            int bb = i >> 4;
            int u = i & 15;
            float ig = sigm(gb[i]);
            float fg = sigm(gb[512 + i]);
            float gg = tanh_(gb[1024 + i]);
            float og = sigm(gb[1536 + i]);
            int idx = bb * NH + U + u;
            float c = fg * cst[idx] + ig * gg;
            cst[idx] = c;
            float h = og * tanh_(c);
            hout[idx] = (f16)h;
            if (stage == 2) h2all[(size_t)t * NB * NH + idx] = (f16)h;
        }
    } else {
        // ---- stage A: xp1[t] = state[:,t,:] @ W_ih0^T + b0, K=128 ----
        int t = k;
        if (t >= NT) return;
        int wg = blk - 192;                     // 0..15, 256 cols each
        int colbase = wg * 256 + wave * 64;
        f32x4 acc[2][4];
#pragma unroll
        for (int nt = 0; nt < 4; ++nt) {
            float bb = b0[colbase + nt * 16 + llo];
#pragma unroll
            for (int r = 0; r < 4; ++r) { acc[0][nt][r] = bb; acc[1][nt][r] = bb; }
        }
#pragma unroll
        for (int kt = 0; kt < 4; ++kt) {
            int kk = kt * 32 + lhi * 8;
            f16x8 a0 = *(const f16x8*)(state16 + ((size_t)llo * NT + t) * NI + kk);
            f16x8 a1 = *(const f16x8*)(state16 + ((size_t)(16 + llo) * NT + t) * NI + kk);
#pragma unroll
            for (int nt = 0; nt < 4; ++nt) {
                int col = colbase + nt * 16 + llo;
                f16x8 bf = *(const f16x8*)(Wih0 + (size_t)col * NI + kk);
                acc[0][nt] = __builtin_amdgcn_mfma_f32_16x16x32_f16(a0, bf, acc[0][nt], 0, 0, 0);
                acc[1][nt] = __builtin_amdgcn_mfma_f32_16x16x32_f16(a1, bf, acc[1][nt], 0, 0, 0);
            }
        }
        float* xo = xp1 + (size_t)(t & 1) * NB * NG;
#pragma unroll
        for (int nt = 0; nt < 4; ++nt) {
            int col = colbase + nt * 16 + llo;
#pragma unroll
            for (int r = 0; r < 4; ++r) {
                xo[(lhi * 4 + r) * NG + col] = acc[0][nt][r];
                xo[(16 + lhi * 4 + r) * NG + col] = acc[1][nt][r];
            }
        }
    }
}

// out[b][t][o] = h2[b][t][:] @ W_out^T + b_out ; one WG per t
__global__ __launch_bounds__(256) void head_kernel(
    const f16* __restrict__ h2all, const f16* __restrict__ Wout,
    const float* __restrict__ bout, float* __restrict__ out)
{
    __shared__ __align__(16) char smem[65536];
    int t = blockIdx.x;
    int tid = threadIdx.x;
    int wave = tid >> 6, lane = tid & 63, lhi = lane >> 4, llo = lane & 15;
    stage_h(h2all + (size_t)t * NB * NH, smem, tid);
    __syncthreads();

    f32x4 acc[2][2];
#pragma unroll
    for (int nt = 0; nt < 2; ++nt) {
        int col = wave * 32 + nt * 16 + llo;
        float bb = bout[col];
#pragma unroll
        for (int r = 0; r < 4; ++r) { acc[0][nt][r] = bb; acc[1][nt][r] = bb; }
    }
#pragma unroll 8
    for (int kt = 0; kt < 32; ++kt) {
        int kk = kt * 32 + lhi * 8;
        f16x8 a0 = afrag(smem, llo, kk);
        f16x8 a1 = afrag(smem, 16 + llo, kk);
#pragma unroll
        for (int nt = 0; nt < 2; ++nt) {
            int col = wave * 32 + nt * 16 + llo;
            f16x8 bf = *(const f16x8*)(Wout + (size_t)col * NH + kk);
            acc[0][nt] = __builtin_amdgcn_mfma_f32_16x16x32_f16(a0, bf, acc[0][nt], 0, 0, 0);
            acc[1][nt] = __builtin_amdgcn_mfma_f32_16x16x32_f16(a1, bf, acc[1][nt], 0, 0, 0);
        }
    }
#pragma unroll
    for (int nt = 0; nt < 2; ++nt) {
        int col = wave * 32 + nt * 16 + llo;
#pragma unroll
        for (int r = 0; r < 4; ++r) {
            out[(size_t)(lhi * 4 + r) * NT * NO + (size_t)t * NO + col] = acc[0][nt][r];
            out[(size_t)(16 + lhi * 4 + r) * NT * NO + (size_t)t * NO + col] = acc[1][nt][r];
        }
    }
}

extern "C" void kernel_launch(void* const* d_in, const int* in_sizes, int n_in,
                              void* d_out, int out_size, void* d_ws, size_t ws_size,
                              hipStream_t stream)
{
    const float* state = (const float*)d_in[0];
    const float* Wih0f = (const float*)d_in[1];
    const float* Whh0f = (const float*)d_in[2];
    const float* b0    = (const float*)d_in[3];
    const float* Wih1f = (const float*)d_in[4];
    const float* Whh1f = (const float*)d_in[5];
    const float* b1    = (const float*)d_in[6];
    const float* Woutf = (const float*)d_in[7];
    const float* bout  = (const float*)d_in[8];
    float* out = (float*)d_out;

    size_t off = 0;
    char* base = (char*)d_ws;
    auto alloc = [&](size_t bytes) -> void* {
        void* p = base + off;
        off += (bytes + 255) & ~(size_t)255;
        return p;
    };
    f16*   state16 = (f16*)alloc((size_t)NB * NT * NI * 2);
    f16*   Wih0    = (f16*)alloc((size_t)NG * NI * 2);
    f16*   Whh0    = (f16*)alloc((size_t)NG * NH * 2);
    f16*   Wih1    = (f16*)alloc((size_t)NG * NH * 2);
    f16*   Whh1    = (f16*)alloc((size_t)NG * NH * 2);
    f16*   Wout    = (f16*)alloc((size_t)NO * NH * 2);
    float* xp1     = (float*)alloc((size_t)2 * NB * NG * 4);
    float* xp2     = (float*)alloc((size_t)2 * NB * NG * 4);
    f16*   h1r     = (f16*)alloc((size_t)2 * NB * NH * 2);
    f16*   h2r     = (f16*)alloc((size_t)2 * NB * NH * 2);
    float* c1      = (float*)alloc((size_t)NB * NH * 4);
    float* c2      = (float*)alloc((size_t)NB * NH * 4);
    f16*   h2all   = (f16*)alloc((size_t)NT * NB * NH * 2);
    (void)ws_size; (void)in_sizes; (void)n_in; (void)out_size;

    auto conv = [&](const float* s, f16* d, int n) {
        convf16<<<(n + 255) / 256, 256, 0, stream>>>(s, d, n);
    };
    conv(state, state16, NB * NT * NI);
    conv(Wih0f, Wih0, NG * NI);
    conv(Whh0f, Whh0, NG * NH);
    conv(Wih1f, Wih1, NG * NH);
    conv(Woutf, Wout, NO * NH);
    conv(Whh1f, Whh1, NG * NH);

    hipMemsetAsync(h1r, 0, (size_t)2 * NB * NH * 2, stream);
    hipMemsetAsync(h2r, 0, (size_t)2 * NB * NH * 2, stream);
    hipMemsetAsync(c1, 0, (size_t)NB * NH * 4, stream);
    hipMemsetAsync(c2, 0, (size_t)NB * NH * 4, stream);

    for (int k = 0; k < NT + 3; ++k) {
        lstm_step<<<208, 256, 0, stream>>>(k, state16, Wih0, Whh0, Wih1, Whh1,
                                           b0, b1, xp1, xp2, h1r, h2r, c1, c2, h2all);
    }
    head_kernel<<<NT, 256, 0, stream>>>(h2all, Wout, bout, out);
}